// Round 1
// baseline (2866.598 us; speedup 1.0000x reference)
//
#include <hip/hip_runtime.h>

#define NN   24000
#define NTP  8000
#define HH   8
#define DKK  16
#define RR   34
#define EPRN 10000
#define NE   (RR*EPRN)     // 340000
#define NEH  (NE*HH)       // 2720000

__device__ __forceinline__ int src_nt(int r){ return r<=9?0:(r<=21?1:2); }
__device__ __forceinline__ int dst_nt(int r){
    if (r<=2)  return 0;
    if (r<=6)  return 1;
    if (r<=9)  return 2;
    if (r<=13) return 0;
    if (r<=17) return 1;
    if (r<=21) return 2;
    if (r<=24) return 0;
    if (r<=28) return 1;
    return 2;
}

// ---------------- K1: typed QKV GEMMs ----------------
// grid (NN/64, 3), block 256. blockIdx.y: 0=k,1=q,2=v
__global__ __launch_bounds__(256) void qkv_gemm(
    const float* __restrict__ x,
    const float* __restrict__ Wk, const float* __restrict__ bk,
    const float* __restrict__ Wq, const float* __restrict__ bq,
    const float* __restrict__ Wv, const float* __restrict__ bv,
    float* __restrict__ qo, float* __restrict__ ko_, float* __restrict__ vo)
{
    __shared__ float xT[16][64];    // [kk][row] transposed x tile
    __shared__ float wS[16][128];   // [kk][col]
    const int rb  = blockIdx.x * 64;
    const int tau = rb / NTP;       // 8000 % 64 == 0 -> uniform per block
    const float* W; const float* b; float* out;
    if      (blockIdx.y == 0) { W = Wk; b = bk; out = ko_; }
    else if (blockIdx.y == 1) { W = Wq; b = bq; out = qo;  }
    else                      { W = Wv; b = bv; out = vo;  }
    W += tau * 128 * 128;
    const int tid = threadIdx.x;
    const int cg  = tid & 31;   // cols 4*cg..+3
    const int rg  = tid >> 5;   // rows 8*rg..+7
    float acc[8][4] = {};
    for (int kb = 0; kb < 128; kb += 16) {
        {   // stage x tile (transposed): 64 rows x 16 k
            int row = tid >> 2, kq = (tid & 3) * 4;
            float4 xv = *(const float4*)(x + (size_t)(rb + row) * 128 + kb + kq);
            xT[kq+0][row] = xv.x; xT[kq+1][row] = xv.y;
            xT[kq+2][row] = xv.z; xT[kq+3][row] = xv.w;
        }
        {   // stage W tile: 16 x 128
            #pragma unroll
            for (int i = 0; i < 2; i++) {
                int f = tid + i * 256; int kk = f >> 5; int c4 = (f & 31) * 4;
                *(float4*)(&wS[kk][c4]) = *(const float4*)(W + (size_t)(kb + kk) * 128 + c4);
            }
        }
        __syncthreads();
        #pragma unroll
        for (int kk = 0; kk < 16; kk++) {
            float4 wv = *(const float4*)(&wS[kk][cg * 4]);
            float xr[8];
            *(float4*)&xr[0] = *(const float4*)(&xT[kk][rg * 8]);
            *(float4*)&xr[4] = *(const float4*)(&xT[kk][rg * 8 + 4]);
            #pragma unroll
            for (int j = 0; j < 8; j++) {
                acc[j][0] += xr[j] * wv.x; acc[j][1] += xr[j] * wv.y;
                acc[j][2] += xr[j] * wv.z; acc[j][3] += xr[j] * wv.w;
            }
        }
        __syncthreads();
    }
    #pragma unroll
    for (int j = 0; j < 8; j++) {
        int row = rb + rg * 8 + j;
        float4 o;
        o.x = acc[j][0] + b[tau * 128 + cg * 4 + 0];
        o.y = acc[j][1] + b[tau * 128 + cg * 4 + 1];
        o.z = acc[j][2] + b[tau * 128 + cg * 4 + 2];
        o.w = acc[j][3] + b[tau * 128 + cg * 4 + 3];
        *(float4*)(out + (size_t)row * 128 + cg * 4) = o;
    }
}

// ---------------- K2: edge attention scores + exp-sum denominator ----------------
// one thread per (edge, head)
__global__ __launch_bounds__(256) void edge_scores(
    const float* __restrict__ q, const float* __restrict__ k,
    const int* __restrict__ src, const int* __restrict__ dst,
    const float* __restrict__ rel_att, const float* __restrict__ rel_pri,
    const float* __restrict__ nta, const float* __restrict__ nta1,
    const float* __restrict__ weightp, const float* __restrict__ attn_w,
    float* __restrict__ sout, float* __restrict__ den)
{
    int t = blockIdx.x * 256 + threadIdx.x;
    if (t >= NEH) return;
    const int h = t & 7, e = t >> 3;
    const int r = e / EPRN;
    const int sn = src[e], dn = dst[e];
    const int stau = src_nt(r), dtau = dst_nt(r);

    float qd[16], ks[16];
    {
        const float4* qp = (const float4*)(q + (size_t)dn * 128 + h * 16);
        const float4* kp = (const float4*)(k + (size_t)sn * 128 + h * 16);
        #pragma unroll
        for (int i = 0; i < 4; i++) { ((float4*)qd)[i] = qp[i]; ((float4*)ks)[i] = kp[i]; }
    }
    const float* A = rel_att + ((size_t)(r * HH + h)) * 256;
    float a = 0.f;
    #pragma unroll
    for (int d = 0; d < 16; d++) {
        const float4* Ar = (const float4*)(A + d * 16);
        float4 a0 = Ar[0], a1 = Ar[1], a2 = Ar[2], a3 = Ar[3];
        float tmp = a0.x*qd[0] + a0.y*qd[1] + a0.z*qd[2] + a0.w*qd[3]
                  + a1.x*qd[4] + a1.y*qd[5] + a1.z*qd[6] + a1.w*qd[7]
                  + a2.x*qd[8] + a2.y*qd[9] + a2.z*qd[10]+ a2.w*qd[11]
                  + a3.x*qd[12]+ a3.y*qd[13]+ a3.z*qd[14]+ a3.w*qd[15];
        a += ks[d] * tmp;
    }
    float qwq = 0.f, kwk = 0.f;
    #pragma unroll
    for (int d = 0; d < 16; d++) { qwq += qd[d] * attn_w[d]; kwk += ks[d] * attn_w[16 + d]; }
    float nax = nta1[dtau] * qwq + nta[stau] * kwk;
    float na  = nax >= 0.f ? nax : 0.01f * nax;           // leaky_relu(0.01)
    float beta = 1.f / (1.f + expf(-weightp[0]));          // sigmoid
    float sv = a * rel_pri[r * HH + h] * 0.25f + beta * na; // /sqrt(16)
    sout[t] = sv;
    int idx = (r * NTP + (dn - dtau * NTP)) * HH + h;
    atomicAdd(&den[idx], expf(sv));
}

// ---------------- K3: att*val accumulation into t_acc ----------------
__global__ __launch_bounds__(256) void edge_accum(
    const float* __restrict__ v,
    const int* __restrict__ src, const int* __restrict__ dst,
    const float* __restrict__ rel_msg,
    const float* __restrict__ sarr, const float* __restrict__ den,
    float* __restrict__ t_acc)
{
    int t = blockIdx.x * 256 + threadIdx.x;
    if (t >= NEH) return;
    const int h = t & 7, e = t >> 3;
    const int r = e / EPRN;
    const int sn = src[e], dn = dst[e];
    const int dtau = dst_nt(r);
    int idx = (r * NTP + (dn - dtau * NTP)) * HH + h;
    float att = expf(sarr[t]) / den[idx];

    float vs[16];
    {
        const float4* vp = (const float4*)(v + (size_t)sn * 128 + h * 16);
        #pragma unroll
        for (int i = 0; i < 4; i++) ((float4*)vs)[i] = vp[i];
    }
    const float* M = rel_msg + ((size_t)(r * HH + h)) * 256;
    float acc[16] = {};
    #pragma unroll
    for (int d = 0; d < 16; d++) {
        const float4* Mr = (const float4*)(M + d * 16);
        float4 m0 = Mr[0], m1 = Mr[1], m2 = Mr[2], m3 = Mr[3];
        float vd = vs[d];
        acc[0] += vd*m0.x; acc[1] += vd*m0.y; acc[2] += vd*m0.z; acc[3] += vd*m0.w;
        acc[4] += vd*m1.x; acc[5] += vd*m1.y; acc[6] += vd*m1.z; acc[7] += vd*m1.w;
        acc[8] += vd*m2.x; acc[9] += vd*m2.y; acc[10]+= vd*m2.z; acc[11]+= vd*m2.w;
        acc[12]+= vd*m3.x; acc[13]+= vd*m3.y; acc[14]+= vd*m3.z; acc[15]+= vd*m3.w;
    }
    float* dp = t_acc + (size_t)dn * 128 + h * 16;
    #pragma unroll
    for (int f = 0; f < 16; f++) atomicAdd(dp + f, att * acc[f]);
}

// ---------------- K4: nrel normalize + typed output GEMM + skip blend ----------------
__global__ __launch_bounds__(256) void final_gemm(
    const float* __restrict__ t_acc, const float* __restrict__ den,
    const float* __restrict__ Wa, const float* __restrict__ ba,
    const float* __restrict__ skip, const float* __restrict__ x,
    float* __restrict__ out)
{
    __shared__ float xT[16][64];
    __shared__ float wS[16][128];
    __shared__ float nrelinv[64];
    const int rb  = blockIdx.x * 64;
    const int tau = rb / NTP;
    const int tid = threadIdx.x;
    if (tid < 64) {
        int nl = rb + tid - tau * NTP;
        int cnt = 0;
        #pragma unroll
        for (int r = 0; r < RR; r++)
            if (dst_nt(r) == tau)
                cnt += (den[(size_t)(r * NTP + nl) * HH] > 0.f) ? 1 : 0;
        nrelinv[tid] = 1.f / (float)(cnt > 1 ? cnt : 1);
    }
    __syncthreads();
    const float* W = Wa + (size_t)tau * 128 * 128;
    const int cg = tid & 31;
    const int rg = tid >> 5;
    float acc[8][4] = {};
    for (int kb = 0; kb < 128; kb += 16) {
        {
            int row = tid >> 2, kq = (tid & 3) * 4;
            float sc = nrelinv[row];
            float4 xv = *(const float4*)(t_acc + (size_t)(rb + row) * 128 + kb + kq);
            xT[kq+0][row] = xv.x * sc; xT[kq+1][row] = xv.y * sc;
            xT[kq+2][row] = xv.z * sc; xT[kq+3][row] = xv.w * sc;
        }
        {
            #pragma unroll
            for (int i = 0; i < 2; i++) {
                int f = tid + i * 256; int kk = f >> 5; int c4 = (f & 31) * 4;
                *(float4*)(&wS[kk][c4]) = *(const float4*)(W + (size_t)(kb + kk) * 128 + c4);
            }
        }
        __syncthreads();
        #pragma unroll
        for (int kk = 0; kk < 16; kk++) {
            float4 wv = *(const float4*)(&wS[kk][cg * 4]);
            float xr[8];
            *(float4*)&xr[0] = *(const float4*)(&xT[kk][rg * 8]);
            *(float4*)&xr[4] = *(const float4*)(&xT[kk][rg * 8 + 4]);
            #pragma unroll
            for (int j = 0; j < 8; j++) {
                acc[j][0] += xr[j] * wv.x; acc[j][1] += xr[j] * wv.y;
                acc[j][2] += xr[j] * wv.z; acc[j][3] += xr[j] * wv.w;
            }
        }
        __syncthreads();
    }
    float alpha = 1.f / (1.f + expf(-skip[tau]));
    float oma = 1.f - alpha;
    #pragma unroll
    for (int j = 0; j < 8; j++) {
        int row = rb + rg * 8 + j;
        float4 xv = *(const float4*)(x + (size_t)row * 128 + cg * 4);
        float4 o;
        o.x = (acc[j][0] + ba[tau*128 + cg*4+0]) * alpha + xv.x * oma;
        o.y = (acc[j][1] + ba[tau*128 + cg*4+1]) * alpha + xv.y * oma;
        o.z = (acc[j][2] + ba[tau*128 + cg*4+2]) * alpha + xv.z * oma;
        o.w = (acc[j][3] + ba[tau*128 + cg*4+3]) * alpha + xv.w * oma;
        *(float4*)(out + (size_t)row * 128 + cg * 4) = o;
    }
}

extern "C" void kernel_launch(void* const* d_in, const int* in_sizes, int n_in,
                              void* d_out, int out_size, void* d_ws, size_t ws_size,
                              hipStream_t stream) {
    const float* x       = (const float*)d_in[0];
    const int*   src     = (const int*)  d_in[1];
    const int*   dst     = (const int*)  d_in[2];
    const float* Wk      = (const float*)d_in[3];
    const float* bk      = (const float*)d_in[4];
    const float* Wq      = (const float*)d_in[5];
    const float* bq      = (const float*)d_in[6];
    const float* Wv      = (const float*)d_in[7];
    const float* bv      = (const float*)d_in[8];
    const float* Wa      = (const float*)d_in[9];
    const float* ba      = (const float*)d_in[10];
    const float* rel_att = (const float*)d_in[11];
    const float* rel_msg = (const float*)d_in[12];
    const float* rel_pri = (const float*)d_in[13];
    const float* nta     = (const float*)d_in[14];
    const float* nta1    = (const float*)d_in[15];
    const float* skip    = (const float*)d_in[16];
    const float* weight  = (const float*)d_in[17];
    const float* attn_w  = (const float*)d_in[18];
    float* out = (float*)d_out;

    float* ws    = (float*)d_ws;
    float* q     = ws;                       // NN*128
    float* k     = q + (size_t)NN * 128;     // NN*128
    float* v     = k + (size_t)NN * 128;     // NN*128
    float* t_acc = v + (size_t)NN * 128;     // NN*128
    float* den   = t_acc + (size_t)NN * 128; // RR*NTP*HH
    float* s     = den + (size_t)RR * NTP * HH; // NE*HH

    // zero t_acc + den (contiguous)
    hipMemsetAsync(t_acc, 0, ((size_t)NN * 128 + (size_t)RR * NTP * HH) * sizeof(float), stream);

    qkv_gemm<<<dim3(NN / 64, 3), 256, 0, stream>>>(x, Wk, bk, Wq, bq, Wv, bv, q, k, v);
    edge_scores<<<NEH / 256, 256, 0, stream>>>(q, k, src, dst, rel_att, rel_pri,
                                               nta, nta1, weight, attn_w, s, den);
    edge_accum<<<NEH / 256, 256, 0, stream>>>(v, src, dst, rel_msg, s, den, t_acc);
    final_gemm<<<NN / 64, 256, 0, stream>>>(t_acc, den, Wa, ba, skip, x, out);
}

// Round 2
// 569.581 us; speedup vs baseline: 5.0328x; 5.0328x over previous
//
#include <hip/hip_runtime.h>

#define NN   24000
#define NTP  8000
#define HH   8
#define DKK  16
#define RR   34
#define EPRN 10000
#define NE   (RR*EPRN)     // 340000
#define NEH  (NE*HH)       // 2720000
#define NB   (RR*NTP)      // 272000 buckets (r, dst_local)
#define NBLK ((NB+255)/256) // 1063

__device__ __forceinline__ int src_nt(int r){ return r<=9?0:(r<=21?1:2); }
__device__ __forceinline__ int dst_nt(int r){
    if (r<=2)  return 0;
    if (r<=6)  return 1;
    if (r<=9)  return 2;
    if (r<=13) return 0;
    if (r<=17) return 1;
    if (r<=21) return 2;
    if (r<=24) return 0;
    if (r<=28) return 1;
    return 2;
}

// ---------------- K1: typed QKV GEMMs ----------------
__global__ __launch_bounds__(256) void qkv_gemm(
    const float* __restrict__ x,
    const float* __restrict__ Wk, const float* __restrict__ bk,
    const float* __restrict__ Wq, const float* __restrict__ bq,
    const float* __restrict__ Wv, const float* __restrict__ bv,
    float* __restrict__ qo, float* __restrict__ ko_, float* __restrict__ vo)
{
    __shared__ float xT[16][68];    // stride 68: 16B-aligned rows, 2-way max bank alias
    __shared__ float wS[16][128];
    const int rb  = blockIdx.x * 64;
    const int tau = rb / NTP;
    const float* W; const float* b; float* out;
    if      (blockIdx.y == 0) { W = Wk; b = bk; out = ko_; }
    else if (blockIdx.y == 1) { W = Wq; b = bq; out = qo;  }
    else                      { W = Wv; b = bv; out = vo;  }
    W += tau * 128 * 128;
    const int tid = threadIdx.x;
    const int cg  = tid & 31;
    const int rg  = tid >> 5;
    float acc[8][4] = {};
    for (int kb = 0; kb < 128; kb += 16) {
        {
            int row = tid >> 2, kq = (tid & 3) * 4;
            float4 xv = *(const float4*)(x + (size_t)(rb + row) * 128 + kb + kq);
            xT[kq+0][row] = xv.x; xT[kq+1][row] = xv.y;
            xT[kq+2][row] = xv.z; xT[kq+3][row] = xv.w;
        }
        {
            #pragma unroll
            for (int i = 0; i < 2; i++) {
                int f = tid + i * 256; int kk = f >> 5; int c4 = (f & 31) * 4;
                *(float4*)(&wS[kk][c4]) = *(const float4*)(W + (size_t)(kb + kk) * 128 + c4);
            }
        }
        __syncthreads();
        #pragma unroll
        for (int kk = 0; kk < 16; kk++) {
            float4 wv = *(const float4*)(&wS[kk][cg * 4]);
            float xr[8];
            *(float4*)&xr[0] = *(const float4*)(&xT[kk][rg * 8]);
            *(float4*)&xr[4] = *(const float4*)(&xT[kk][rg * 8 + 4]);
            #pragma unroll
            for (int j = 0; j < 8; j++) {
                acc[j][0] += xr[j] * wv.x; acc[j][1] += xr[j] * wv.y;
                acc[j][2] += xr[j] * wv.z; acc[j][3] += xr[j] * wv.w;
            }
        }
        __syncthreads();
    }
    #pragma unroll
    for (int j = 0; j < 8; j++) {
        int row = rb + rg * 8 + j;
        float4 o;
        o.x = acc[j][0] + b[tau * 128 + cg * 4 + 0];
        o.y = acc[j][1] + b[tau * 128 + cg * 4 + 1];
        o.z = acc[j][2] + b[tau * 128 + cg * 4 + 2];
        o.w = acc[j][3] + b[tau * 128 + cg * 4 + 3];
        *(float4*)(out + (size_t)row * 128 + cg * 4) = o;
    }
}

// ---------------- Sort: histogram ----------------
__global__ __launch_bounds__(256) void hist_kernel(const int* __restrict__ dst,
                                                   int* __restrict__ counts)
{
    int e = blockIdx.x * 256 + threadIdx.x;
    if (e >= NE) return;
    int r = e / EPRN;
    int b = r * NTP + (dst[e] - dst_nt(r) * NTP);
    atomicAdd(&counts[b], 1);
}

// ---------------- Sort: per-256-chunk sums ----------------
__global__ __launch_bounds__(256) void bsum_kernel(const int* __restrict__ counts,
                                                   int* __restrict__ bsum)
{
    __shared__ int sm[256];
    int i = blockIdx.x * 256 + threadIdx.x;
    sm[threadIdx.x] = (i < NB) ? counts[i] : 0;
    __syncthreads();
    for (int s = 128; s > 0; s >>= 1) {
        if (threadIdx.x < s) sm[threadIdx.x] += sm[threadIdx.x + s];
        __syncthreads();
    }
    if (threadIdx.x == 0) bsum[blockIdx.x] = sm[0];
}

// ---------------- Sort: exclusive scan of block sums (single wave) ----------------
__global__ __launch_bounds__(64) void scanb_kernel(int* __restrict__ bsum)
{
    int lane = threadIdx.x;
    int base = 0;
    for (int start = 0; start < NBLK; start += 64) {
        int i = start + lane;
        int val = (i < NBLK) ? bsum[i] : 0;
        int incl = val;
        #pragma unroll
        for (int d = 1; d < 64; d <<= 1) {
            int other = __shfl_up(incl, d, 64);
            if (lane >= d) incl += other;
        }
        if (i < NBLK) bsum[i] = base + (incl - val);
        base += __shfl(incl, 63, 64);
    }
}

// ---------------- Sort: per-bucket offsets + scatter cursor ----------------
__global__ __launch_bounds__(256) void offsets_kernel(
    const int* __restrict__ counts, const int* __restrict__ bsumx,
    int* __restrict__ offs, int* __restrict__ cursor)
{
    __shared__ int sm[256];
    int tid = threadIdx.x;
    int i = blockIdx.x * 256 + tid;
    int v = (i < NB) ? counts[i] : 0;
    sm[tid] = v;
    __syncthreads();
    for (int d = 1; d < 256; d <<= 1) {
        int t = (tid >= d) ? sm[tid - d] : 0;
        __syncthreads();
        sm[tid] += t;
        __syncthreads();
    }
    int excl = sm[tid] - v;
    int base = bsumx[blockIdx.x];
    if (i < NB) { offs[i] = base + excl; cursor[i] = base + excl; }
}

// ---------------- Sort: scatter edge ids (+src) into sorted order ----------------
__global__ __launch_bounds__(256) void scatter_kernel(
    const int* __restrict__ src, const int* __restrict__ dst,
    int* __restrict__ cursor, int* __restrict__ eid, int* __restrict__ esrc)
{
    int e = blockIdx.x * 256 + threadIdx.x;
    if (e >= NE) return;
    int r = e / EPRN;
    int b = r * NTP + (dst[e] - dst_nt(r) * NTP);
    int pos = atomicAdd(&cursor[b], 1);
    eid[pos] = e;
    esrc[pos] = src[e];
}

// ---------------- K2: edge attention scores (sorted order, no atomics) ----------------
__global__ __launch_bounds__(256) void edge_scores(
    const float* __restrict__ q, const float* __restrict__ k,
    const int* __restrict__ eid, const int* __restrict__ esrc,
    const int* __restrict__ dst,
    const float* __restrict__ rel_att, const float* __restrict__ rel_pri,
    const float* __restrict__ nta, const float* __restrict__ nta1,
    const float* __restrict__ weightp, const float* __restrict__ attn_w,
    float* __restrict__ sout)
{
    int t = blockIdx.x * 256 + threadIdx.x;   // t = slot*8 + h
    const int h = t & 7, slot = t >> 3;
    const int r = slot / EPRN;                 // each relation holds exactly EPRN slots
    const int e = eid[slot];
    const int sn = esrc[slot], dn = dst[e];
    const int stau = src_nt(r), dtau = dst_nt(r);

    float qd[16], ks[16];
    {
        const float4* qp = (const float4*)(q + (size_t)dn * 128 + h * 16);
        const float4* kp = (const float4*)(k + (size_t)sn * 128 + h * 16);
        #pragma unroll
        for (int i = 0; i < 4; i++) { ((float4*)qd)[i] = qp[i]; ((float4*)ks)[i] = kp[i]; }
    }
    const float* A = rel_att + ((size_t)(r * HH + h)) * 256;
    float a = 0.f;
    #pragma unroll
    for (int d = 0; d < 16; d++) {
        const float4* Ar = (const float4*)(A + d * 16);
        float4 a0 = Ar[0], a1 = Ar[1], a2 = Ar[2], a3 = Ar[3];
        float tmp = a0.x*qd[0] + a0.y*qd[1] + a0.z*qd[2] + a0.w*qd[3]
                  + a1.x*qd[4] + a1.y*qd[5] + a1.z*qd[6] + a1.w*qd[7]
                  + a2.x*qd[8] + a2.y*qd[9] + a2.z*qd[10]+ a2.w*qd[11]
                  + a3.x*qd[12]+ a3.y*qd[13]+ a3.z*qd[14]+ a3.w*qd[15];
        a += ks[d] * tmp;
    }
    float qwq = 0.f, kwk = 0.f;
    #pragma unroll
    for (int d = 0; d < 16; d++) { qwq += qd[d] * attn_w[d]; kwk += ks[d] * attn_w[16 + d]; }
    float nax = nta1[dtau] * qwq + nta[stau] * kwk;
    float na  = nax >= 0.f ? nax : 0.01f * nax;
    float beta = 1.f / (1.f + expf(-weightp[0]));
    sout[t] = a * rel_pri[r * HH + h] * 0.25f + beta * na;
}

// ---------------- K3: gather-aggregate per (dst, head) — no atomics ----------------
__global__ __launch_bounds__(256) void gather_kernel(
    const float* __restrict__ v, const float* __restrict__ s,
    const int* __restrict__ esrc, const int* __restrict__ offs,
    const int* __restrict__ counts,
    const float* __restrict__ rel_msg, float* __restrict__ t_acc)
{
    __shared__ float Msh[8][260];   // stride 260 -> 8 heads on disjoint banks
    const int idx = blockIdx.x * 256 + threadIdx.x;   // (dst, h)
    const int dn = idx >> 3, h = idx & 7;
    const int dtau = dn / NTP;       // uniform per block (8000*8 % 256 == 0)
    const int dl = dn - dtau * NTP;

    float th[16] = {};
    int nrel = 0;
    for (int r = 0; r < RR; r++) {
        if (dst_nt(r) != dtau) continue;     // uniform branch
        __syncthreads();
        {
            const float* Mr = rel_msg + (size_t)r * HH * 256;
            #pragma unroll
            for (int i = threadIdx.x; i < 2048; i += 256)
                Msh[i >> 8][i & 255] = Mr[i];
        }
        __syncthreads();
        const int b = r * NTP + dl;
        const int beg = offs[b], cnt = counts[b];
        if (cnt > 0) {
            nrel++;
            float den = 0.f;
            float macc[16] = {};
            for (int j = 0; j < cnt; j++) {
                const int slot = beg + j;
                float es = expf(s[(size_t)slot * 8 + h]);
                den += es;
                const int sn = esrc[slot];
                float vv[16];
                const float4* vp = (const float4*)(v + (size_t)sn * 128 + h * 16);
                #pragma unroll
                for (int i = 0; i < 4; i++) ((float4*)vv)[i] = vp[i];
                #pragma unroll
                for (int f = 0; f < 16; f++) macc[f] += es * vv[f];
            }
            const float inv = 1.f / den;
            #pragma unroll
            for (int d = 0; d < 16; d++) {
                float md = macc[d] * inv;
                #pragma unroll
                for (int f = 0; f < 16; f++) th[f] += md * Msh[h][d * 16 + f];
            }
        }
    }
    const float innv = 1.f / (float)(nrel > 1 ? nrel : 1);
    float* op = t_acc + (size_t)dn * 128 + h * 16;
    #pragma unroll
    for (int f = 0; f < 16; f++) op[f] = th[f] * innv;
}

// ---------------- K4: typed output GEMM + skip blend ----------------
__global__ __launch_bounds__(256) void final_gemm(
    const float* __restrict__ t_acc,
    const float* __restrict__ Wa, const float* __restrict__ ba,
    const float* __restrict__ skip, const float* __restrict__ x,
    float* __restrict__ out)
{
    __shared__ float xT[16][68];
    __shared__ float wS[16][128];
    const int rb  = blockIdx.x * 64;
    const int tau = rb / NTP;
    const int tid = threadIdx.x;
    const float* W = Wa + (size_t)tau * 128 * 128;
    const int cg = tid & 31;
    const int rg = tid >> 5;
    float acc[8][4] = {};
    for (int kb = 0; kb < 128; kb += 16) {
        {
            int row = tid >> 2, kq = (tid & 3) * 4;
            float4 xv = *(const float4*)(t_acc + (size_t)(rb + row) * 128 + kb + kq);
            xT[kq+0][row] = xv.x; xT[kq+1][row] = xv.y;
            xT[kq+2][row] = xv.z; xT[kq+3][row] = xv.w;
        }
        {
            #pragma unroll
            for (int i = 0; i < 2; i++) {
                int f = tid + i * 256; int kk = f >> 5; int c4 = (f & 31) * 4;
                *(float4*)(&wS[kk][c4]) = *(const float4*)(W + (size_t)(kb + kk) * 128 + c4);
            }
        }
        __syncthreads();
        #pragma unroll
        for (int kk = 0; kk < 16; kk++) {
            float4 wv = *(const float4*)(&wS[kk][cg * 4]);
            float xr[8];
            *(float4*)&xr[0] = *(const float4*)(&xT[kk][rg * 8]);
            *(float4*)&xr[4] = *(const float4*)(&xT[kk][rg * 8 + 4]);
            #pragma unroll
            for (int j = 0; j < 8; j++) {
                acc[j][0] += xr[j] * wv.x; acc[j][1] += xr[j] * wv.y;
                acc[j][2] += xr[j] * wv.z; acc[j][3] += xr[j] * wv.w;
            }
        }
        __syncthreads();
    }
    float alpha = 1.f / (1.f + expf(-skip[tau]));
    float oma = 1.f - alpha;
    #pragma unroll
    for (int j = 0; j < 8; j++) {
        int row = rb + rg * 8 + j;
        float4 xv = *(const float4*)(x + (size_t)row * 128 + cg * 4);
        float4 o;
        o.x = (acc[j][0] + ba[tau*128 + cg*4+0]) * alpha + xv.x * oma;
        o.y = (acc[j][1] + ba[tau*128 + cg*4+1]) * alpha + xv.y * oma;
        o.z = (acc[j][2] + ba[tau*128 + cg*4+2]) * alpha + xv.z * oma;
        o.w = (acc[j][3] + ba[tau*128 + cg*4+3]) * alpha + xv.w * oma;
        *(float4*)(out + (size_t)row * 128 + cg * 4) = o;
    }
}

extern "C" void kernel_launch(void* const* d_in, const int* in_sizes, int n_in,
                              void* d_out, int out_size, void* d_ws, size_t ws_size,
                              hipStream_t stream) {
    const float* x       = (const float*)d_in[0];
    const int*   src     = (const int*)  d_in[1];
    const int*   dst     = (const int*)  d_in[2];
    const float* Wk      = (const float*)d_in[3];
    const float* bk      = (const float*)d_in[4];
    const float* Wq      = (const float*)d_in[5];
    const float* bq      = (const float*)d_in[6];
    const float* Wv      = (const float*)d_in[7];
    const float* bv      = (const float*)d_in[8];
    const float* Wa      = (const float*)d_in[9];
    const float* ba      = (const float*)d_in[10];
    const float* rel_att = (const float*)d_in[11];
    const float* rel_msg = (const float*)d_in[12];
    const float* rel_pri = (const float*)d_in[13];
    const float* nta     = (const float*)d_in[14];
    const float* nta1    = (const float*)d_in[15];
    const float* skip    = (const float*)d_in[16];
    const float* weight  = (const float*)d_in[17];
    const float* attn_w  = (const float*)d_in[18];
    float* out = (float*)d_out;

    float* ws    = (float*)d_ws;
    float* q     = ws;                           // NN*128
    float* k     = q + (size_t)NN * 128;
    float* v     = k + (size_t)NN * 128;
    float* t_acc = v + (size_t)NN * 128;
    float* s     = t_acc + (size_t)NN * 128;     // NEH
    int* counts  = (int*)(s + (size_t)NEH);      // NB
    int* offs    = counts + NB;                  // NB
    int* cursor  = offs + NB;                    // NB
    int* bsum    = cursor + NB;                  // NBLK (pad to 1064)
    int* eid     = bsum + 1064;                  // NE
    int* esrc    = eid + NE;                     // NE

    hipMemsetAsync(counts, 0, (size_t)NB * sizeof(int), stream);

    qkv_gemm<<<dim3(NN / 64, 3), 256, 0, stream>>>(x, Wk, bk, Wq, bq, Wv, bv, q, k, v);
    hist_kernel<<<(NE + 255) / 256, 256, 0, stream>>>(dst, counts);
    bsum_kernel<<<NBLK, 256, 0, stream>>>(counts, bsum);
    scanb_kernel<<<1, 64, 0, stream>>>(bsum);
    offsets_kernel<<<NBLK, 256, 0, stream>>>(counts, bsum, offs, cursor);
    scatter_kernel<<<(NE + 255) / 256, 256, 0, stream>>>(src, dst, cursor, eid, esrc);
    edge_scores<<<NEH / 256, 256, 0, stream>>>(q, k, eid, esrc, dst, rel_att, rel_pri,
                                               nta, nta1, weight, attn_w, s);
    gather_kernel<<<(NN * HH) / 256, 256, 0, stream>>>(v, s, esrc, offs, counts,
                                                       rel_msg, t_acc);
    final_gemm<<<NN / 64, 256, 0, stream>>>(t_acc, Wa, ba, skip, x, out);
}

// Round 3
// 342.345 us; speedup vs baseline: 8.3734x; 1.6638x over previous
//
#include <hip/hip_runtime.h>

#define NN   24000
#define NTP  8000
#define HH   8
#define DKK  16
#define RR   34
#define EPRN 10000
#define NE   (RR*EPRN)     // 340000
#define NEH  (NE*HH)       // 2720000
#define NB   (RR*NTP)      // 272000 buckets (r, dst_local)
#define NBLK ((NB+255)/256) // 1063

__device__ __forceinline__ int src_nt(int r){ return r<=9?0:(r<=21?1:2); }
__device__ __forceinline__ int dst_nt(int r){
    if (r<=2)  return 0;
    if (r<=6)  return 1;
    if (r<=9)  return 2;
    if (r<=13) return 0;
    if (r<=17) return 1;
    if (r<=21) return 2;
    if (r<=24) return 0;
    if (r<=28) return 1;
    return 2;
}

// ---------------- K1: typed QKV GEMMs ----------------
__global__ __launch_bounds__(256) void qkv_gemm(
    const float* __restrict__ x,
    const float* __restrict__ Wk, const float* __restrict__ bk,
    const float* __restrict__ Wq, const float* __restrict__ bq,
    const float* __restrict__ Wv, const float* __restrict__ bv,
    float* __restrict__ qo, float* __restrict__ ko_, float* __restrict__ vo)
{
    __shared__ float xT[16][68];
    __shared__ float wS[16][128];
    const int rb  = blockIdx.x * 64;
    const int tau = rb / NTP;
    const float* W; const float* b; float* out;
    if      (blockIdx.y == 0) { W = Wk; b = bk; out = ko_; }
    else if (blockIdx.y == 1) { W = Wq; b = bq; out = qo;  }
    else                      { W = Wv; b = bv; out = vo;  }
    W += tau * 128 * 128;
    const int tid = threadIdx.x;
    const int cg  = tid & 31;
    const int rg  = tid >> 5;
    float acc[8][4] = {};
    for (int kb = 0; kb < 128; kb += 16) {
        {
            int row = tid >> 2, kq = (tid & 3) * 4;
            float4 xv = *(const float4*)(x + (size_t)(rb + row) * 128 + kb + kq);
            xT[kq+0][row] = xv.x; xT[kq+1][row] = xv.y;
            xT[kq+2][row] = xv.z; xT[kq+3][row] = xv.w;
        }
        {
            #pragma unroll
            for (int i = 0; i < 2; i++) {
                int f = tid + i * 256; int kk = f >> 5; int c4 = (f & 31) * 4;
                *(float4*)(&wS[kk][c4]) = *(const float4*)(W + (size_t)(kb + kk) * 128 + c4);
            }
        }
        __syncthreads();
        #pragma unroll
        for (int kk = 0; kk < 16; kk++) {
            float4 wv = *(const float4*)(&wS[kk][cg * 4]);
            float xr[8];
            *(float4*)&xr[0] = *(const float4*)(&xT[kk][rg * 8]);
            *(float4*)&xr[4] = *(const float4*)(&xT[kk][rg * 8 + 4]);
            #pragma unroll
            for (int j = 0; j < 8; j++) {
                acc[j][0] += xr[j] * wv.x; acc[j][1] += xr[j] * wv.y;
                acc[j][2] += xr[j] * wv.z; acc[j][3] += xr[j] * wv.w;
            }
        }
        __syncthreads();
    }
    #pragma unroll
    for (int j = 0; j < 8; j++) {
        int row = rb + rg * 8 + j;
        float4 o;
        o.x = acc[j][0] + b[tau * 128 + cg * 4 + 0];
        o.y = acc[j][1] + b[tau * 128 + cg * 4 + 1];
        o.z = acc[j][2] + b[tau * 128 + cg * 4 + 2];
        o.w = acc[j][3] + b[tau * 128 + cg * 4 + 3];
        *(float4*)(out + (size_t)row * 128 + cg * 4) = o;
    }
}

// ---------------- Sort: histogram ----------------
__global__ __launch_bounds__(256) void hist_kernel(const int* __restrict__ dst,
                                                   int* __restrict__ counts)
{
    int e = blockIdx.x * 256 + threadIdx.x;
    if (e >= NE) return;
    int r = e / EPRN;
    int b = r * NTP + (dst[e] - dst_nt(r) * NTP);
    atomicAdd(&counts[b], 1);
}

// ---------------- Sort: per-256-chunk sums ----------------
__global__ __launch_bounds__(256) void bsum_kernel(const int* __restrict__ counts,
                                                   int* __restrict__ bsum)
{
    __shared__ int sm[256];
    int i = blockIdx.x * 256 + threadIdx.x;
    sm[threadIdx.x] = (i < NB) ? counts[i] : 0;
    __syncthreads();
    for (int s = 128; s > 0; s >>= 1) {
        if (threadIdx.x < s) sm[threadIdx.x] += sm[threadIdx.x + s];
        __syncthreads();
    }
    if (threadIdx.x == 0) bsum[blockIdx.x] = sm[0];
}

// ---------------- Sort: exclusive scan of block sums (single wave) ----------------
__global__ __launch_bounds__(64) void scanb_kernel(int* __restrict__ bsum)
{
    int lane = threadIdx.x;
    int base = 0;
    for (int start = 0; start < NBLK; start += 64) {
        int i = start + lane;
        int val = (i < NBLK) ? bsum[i] : 0;
        int incl = val;
        #pragma unroll
        for (int d = 1; d < 64; d <<= 1) {
            int other = __shfl_up(incl, d, 64);
            if (lane >= d) incl += other;
        }
        if (i < NBLK) bsum[i] = base + (incl - val);
        base += __shfl(incl, 63, 64);
    }
}

// ---------------- Sort: per-bucket offsets + scatter cursor ----------------
__global__ __launch_bounds__(256) void offsets_kernel(
    const int* __restrict__ counts, const int* __restrict__ bsumx,
    int* __restrict__ offs, int* __restrict__ cursor)
{
    __shared__ int sm[256];
    int tid = threadIdx.x;
    int i = blockIdx.x * 256 + tid;
    int v = (i < NB) ? counts[i] : 0;
    sm[tid] = v;
    __syncthreads();
    for (int d = 1; d < 256; d <<= 1) {
        int t = (tid >= d) ? sm[tid - d] : 0;
        __syncthreads();
        sm[tid] += t;
        __syncthreads();
    }
    int excl = sm[tid] - v;
    int base = bsumx[blockIdx.x];
    if (i < NB) { offs[i] = base + excl; cursor[i] = base + excl; }
}

// ---------------- Sort: scatter src+dst into sorted order ----------------
__global__ __launch_bounds__(256) void scatter_kernel(
    const int* __restrict__ src, const int* __restrict__ dst,
    int* __restrict__ cursor, int* __restrict__ esrc, int* __restrict__ edst)
{
    int e = blockIdx.x * 256 + threadIdx.x;
    if (e >= NE) return;
    int r = e / EPRN;
    int d = dst[e];
    int b = r * NTP + (d - dst_nt(r) * NTP);
    int pos = atomicAdd(&cursor[b], 1);
    esrc[pos] = src[e];
    edst[pos] = d;
}

// ---------------- K2: edge attention exp-scores ----------------
// grid (157, 34), block 256 = 32 (slot-pairs) x 8 heads; 2 edges per thread.
// rel_att[r] staged in LDS, padded so the 8 heads hit disjoint bank groups.
__global__ __launch_bounds__(256) void edge_scores(
    const float* __restrict__ q, const float* __restrict__ k,
    const int* __restrict__ esrc, const int* __restrict__ edst,
    const float* __restrict__ rel_att, const float* __restrict__ rel_pri,
    const float* __restrict__ nta, const float* __restrict__ nta1,
    const float* __restrict__ weightp, const float* __restrict__ attn_w,
    float* __restrict__ es_out)
{
    __shared__ float Ash[8][260];   // stride 260: head h starts at bank 4h
    const int r   = blockIdx.y;
    const int tid = threadIdx.x;
    {   // stage rel_att[r]: 8 heads x 256
        const float* Ar = rel_att + (size_t)r * (HH * 256);
        int hh = tid >> 5, j = (tid & 31) * 8;
        float4 a0 = *(const float4*)(Ar + hh * 256 + j);
        float4 a1 = *(const float4*)(Ar + hh * 256 + j + 4);
        *(float4*)(&Ash[hh][j])     = a0;
        *(float4*)(&Ash[hh][j + 4]) = a1;
    }
    __syncthreads();

    const int h  = tid & 7;
    const int sl = tid >> 3;              // 0..31
    const int l0 = blockIdx.x * 64 + sl;  // local slots l0, l0+32
    const int l1 = l0 + 32;
    const bool v0 = l0 < EPRN, v1 = l1 < EPRN;
    const int s0 = r * EPRN + (v0 ? l0 : 0);
    const int s1 = r * EPRN + (v1 ? l1 : 0);
    const int stau = src_nt(r), dtau = dst_nt(r);

    float q0[16], k0[16], q1[16], k1[16];
    {
        const float4* qp0 = (const float4*)(q + (size_t)edst[s0] * 128 + h * 16);
        const float4* kp0 = (const float4*)(k + (size_t)esrc[s0] * 128 + h * 16);
        const float4* qp1 = (const float4*)(q + (size_t)edst[s1] * 128 + h * 16);
        const float4* kp1 = (const float4*)(k + (size_t)esrc[s1] * 128 + h * 16);
        #pragma unroll
        for (int i = 0; i < 4; i++) {
            ((float4*)q0)[i] = qp0[i]; ((float4*)k0)[i] = kp0[i];
            ((float4*)q1)[i] = qp1[i]; ((float4*)k1)[i] = kp1[i];
        }
    }

    float a0 = 0.f, a1 = 0.f;
    #pragma unroll
    for (int d = 0; d < 16; d++) {
        float4 A0 = *(const float4*)(&Ash[h][d * 16 + 0]);
        float4 A1 = *(const float4*)(&Ash[h][d * 16 + 4]);
        float4 A2 = *(const float4*)(&Ash[h][d * 16 + 8]);
        float4 A3 = *(const float4*)(&Ash[h][d * 16 + 12]);
        float t0 = A0.x*q0[0] + A0.y*q0[1] + A0.z*q0[2] + A0.w*q0[3]
                 + A1.x*q0[4] + A1.y*q0[5] + A1.z*q0[6] + A1.w*q0[7]
                 + A2.x*q0[8] + A2.y*q0[9] + A2.z*q0[10]+ A2.w*q0[11]
                 + A3.x*q0[12]+ A3.y*q0[13]+ A3.z*q0[14]+ A3.w*q0[15];
        a0 += k0[d] * t0;
        float t1 = A0.x*q1[0] + A0.y*q1[1] + A0.z*q1[2] + A0.w*q1[3]
                 + A1.x*q1[4] + A1.y*q1[5] + A1.z*q1[6] + A1.w*q1[7]
                 + A2.x*q1[8] + A2.y*q1[9] + A2.z*q1[10]+ A2.w*q1[11]
                 + A3.x*q1[12]+ A3.y*q1[13]+ A3.z*q1[14]+ A3.w*q1[15];
        a1 += k1[d] * t1;
    }

    float qw0 = 0.f, kw0 = 0.f, qw1 = 0.f, kw1 = 0.f;
    #pragma unroll
    for (int d = 0; d < 16; d++) {
        float wq = attn_w[d], wk = attn_w[16 + d];
        qw0 += q0[d] * wq; kw0 += k0[d] * wk;
        qw1 += q1[d] * wq; kw1 += k1[d] * wk;
    }
    const float c1 = nta1[dtau], c0 = nta[stau];
    const float beta = 1.f / (1.f + expf(-weightp[0]));
    const float pri  = rel_pri[r * HH + h] * 0.25f;
    float na0x = c1 * qw0 + c0 * kw0;
    float na1x = c1 * qw1 + c0 * kw1;
    float na0 = na0x >= 0.f ? na0x : 0.01f * na0x;
    float na1 = na1x >= 0.f ? na1x : 0.01f * na1x;
    if (v0) es_out[(size_t)s0 * 8 + h] = expf(a0 * pri + beta * na0);
    if (v1) es_out[(size_t)s1 * 8 + h] = expf(a1 * pri + beta * na1);
}

// ---------------- K3: gather-aggregate per (dst, head) — no atomics ----------------
__global__ __launch_bounds__(256) void gather_kernel(
    const float* __restrict__ v, const float* __restrict__ es,
    const int* __restrict__ esrc, const int* __restrict__ offs,
    const int* __restrict__ counts,
    const float* __restrict__ rel_msg, float* __restrict__ t_acc)
{
    __shared__ float Msh[8][260];
    const int idx = blockIdx.x * 256 + threadIdx.x;   // (dst, h)
    const int dn = idx >> 3, h = idx & 7;
    const int dtau = dn / NTP;       // uniform per block
    const int dl = dn - dtau * NTP;

    float th[16] = {};
    int nrel = 0;
    for (int r = 0; r < RR; r++) {
        if (dst_nt(r) != dtau) continue;
        __syncthreads();
        {
            const float* Mr = rel_msg + (size_t)r * HH * 256;
            int hh = threadIdx.x >> 5, j = (threadIdx.x & 31) * 8;
            *(float4*)(&Msh[hh][j])     = *(const float4*)(Mr + hh * 256 + j);
            *(float4*)(&Msh[hh][j + 4]) = *(const float4*)(Mr + hh * 256 + j + 4);
        }
        __syncthreads();
        const int b = r * NTP + dl;
        const int beg = offs[b], cnt = counts[b];
        if (cnt > 0) {
            nrel++;
            float den = 0.f;
            float macc[16] = {};
            for (int j = 0; j < cnt; j++) {
                const int slot = beg + j;
                float e = es[(size_t)slot * 8 + h];
                den += e;
                const int sn = esrc[slot];
                float vv[16];
                const float4* vp = (const float4*)(v + (size_t)sn * 128 + h * 16);
                #pragma unroll
                for (int i = 0; i < 4; i++) ((float4*)vv)[i] = vp[i];
                #pragma unroll
                for (int f = 0; f < 16; f++) macc[f] += e * vv[f];
            }
            const float inv = 1.f / den;
            #pragma unroll
            for (int d = 0; d < 16; d++) {
                float md = macc[d] * inv;
                #pragma unroll
                for (int f = 0; f < 16; f++) th[f] += md * Msh[h][d * 16 + f];
            }
        }
    }
    const float innv = 1.f / (float)(nrel > 1 ? nrel : 1);
    float* op = t_acc + (size_t)dn * 128 + h * 16;
    #pragma unroll
    for (int f = 0; f < 16; f++) op[f] = th[f] * innv;
}

// ---------------- K4: typed output GEMM + skip blend ----------------
__global__ __launch_bounds__(256) void final_gemm(
    const float* __restrict__ t_acc,
    const float* __restrict__ Wa, const float* __restrict__ ba,
    const float* __restrict__ skip, const float* __restrict__ x,
    float* __restrict__ out)
{
    __shared__ float xT[16][68];
    __shared__ float wS[16][128];
    const int rb  = blockIdx.x * 64;
    const int tau = rb / NTP;
    const int tid = threadIdx.x;
    const float* W = Wa + (size_t)tau * 128 * 128;
    const int cg = tid & 31;
    const int rg = tid >> 5;
    float acc[8][4] = {};
    for (int kb = 0; kb < 128; kb += 16) {
        {
            int row = tid >> 2, kq = (tid & 3) * 4;
            float4 xv = *(const float4*)(t_acc + (size_t)(rb + row) * 128 + kb + kq);
            xT[kq+0][row] = xv.x; xT[kq+1][row] = xv.y;
            xT[kq+2][row] = xv.z; xT[kq+3][row] = xv.w;
        }
        {
            #pragma unroll
            for (int i = 0; i < 2; i++) {
                int f = tid + i * 256; int kk = f >> 5; int c4 = (f & 31) * 4;
                *(float4*)(&wS[kk][c4]) = *(const float4*)(W + (size_t)(kb + kk) * 128 + c4);
            }
        }
        __syncthreads();
        #pragma unroll
        for (int kk = 0; kk < 16; kk++) {
            float4 wv = *(const float4*)(&wS[kk][cg * 4]);
            float xr[8];
            *(float4*)&xr[0] = *(const float4*)(&xT[kk][rg * 8]);
            *(float4*)&xr[4] = *(const float4*)(&xT[kk][rg * 8 + 4]);
            #pragma unroll
            for (int j = 0; j < 8; j++) {
                acc[j][0] += xr[j] * wv.x; acc[j][1] += xr[j] * wv.y;
                acc[j][2] += xr[j] * wv.z; acc[j][3] += xr[j] * wv.w;
            }
        }
        __syncthreads();
    }
    float alpha = 1.f / (1.f + expf(-skip[tau]));
    float oma = 1.f - alpha;
    #pragma unroll
    for (int j = 0; j < 8; j++) {
        int row = rb + rg * 8 + j;
        float4 xv = *(const float4*)(x + (size_t)row * 128 + cg * 4);
        float4 o;
        o.x = (acc[j][0] + ba[tau*128 + cg*4+0]) * alpha + xv.x * oma;
        o.y = (acc[j][1] + ba[tau*128 + cg*4+1]) * alpha + xv.y * oma;
        o.z = (acc[j][2] + ba[tau*128 + cg*4+2]) * alpha + xv.z * oma;
        o.w = (acc[j][3] + ba[tau*128 + cg*4+3]) * alpha + xv.w * oma;
        *(float4*)(out + (size_t)row * 128 + cg * 4) = o;
    }
}

extern "C" void kernel_launch(void* const* d_in, const int* in_sizes, int n_in,
                              void* d_out, int out_size, void* d_ws, size_t ws_size,
                              hipStream_t stream) {
    const float* x       = (const float*)d_in[0];
    const int*   src     = (const int*)  d_in[1];
    const int*   dst     = (const int*)  d_in[2];
    const float* Wk      = (const float*)d_in[3];
    const float* bk      = (const float*)d_in[4];
    const float* Wq      = (const float*)d_in[5];
    const float* bq      = (const float*)d_in[6];
    const float* Wv      = (const float*)d_in[7];
    const float* bv      = (const float*)d_in[8];
    const float* Wa      = (const float*)d_in[9];
    const float* ba      = (const float*)d_in[10];
    const float* rel_att = (const float*)d_in[11];
    const float* rel_msg = (const float*)d_in[12];
    const float* rel_pri = (const float*)d_in[13];
    const float* nta     = (const float*)d_in[14];
    const float* nta1    = (const float*)d_in[15];
    const float* skip    = (const float*)d_in[16];
    const float* weight  = (const float*)d_in[17];
    const float* attn_w  = (const float*)d_in[18];
    float* out = (float*)d_out;

    float* ws    = (float*)d_ws;
    float* q     = ws;                           // NN*128
    float* k     = q + (size_t)NN * 128;
    float* v     = k + (size_t)NN * 128;
    float* t_acc = v + (size_t)NN * 128;
    float* s     = t_acc + (size_t)NN * 128;     // NEH (holds exp(s))
    int* counts  = (int*)(s + (size_t)NEH);      // NB
    int* offs    = counts + NB;                  // NB
    int* cursor  = offs + NB;                    // NB
    int* bsum    = cursor + NB;                  // NBLK (pad to 1064)
    int* esrc    = bsum + 1064;                  // NE
    int* edst    = esrc + NE;                    // NE

    hipMemsetAsync(counts, 0, (size_t)NB * sizeof(int), stream);

    qkv_gemm<<<dim3(NN / 64, 3), 256, 0, stream>>>(x, Wk, bk, Wq, bq, Wv, bv, q, k, v);
    hist_kernel<<<(NE + 255) / 256, 256, 0, stream>>>(dst, counts);
    bsum_kernel<<<NBLK, 256, 0, stream>>>(counts, bsum);
    scanb_kernel<<<1, 64, 0, stream>>>(bsum);
    offsets_kernel<<<NBLK, 256, 0, stream>>>(counts, bsum, offs, cursor);
    scatter_kernel<<<(NE + 255) / 256, 256, 0, stream>>>(src, dst, cursor, esrc, edst);
    edge_scores<<<dim3((EPRN + 63) / 64, RR), 256, 0, stream>>>(
        q, k, esrc, edst, rel_att, rel_pri, nta, nta1, weight, attn_w, s);
    gather_kernel<<<(NN * HH) / 256, 256, 0, stream>>>(v, s, esrc, offs, counts,
                                                       rel_msg, t_acc);
    final_gemm<<<NN / 64, 256, 0, stream>>>(t_acc, Wa, ba, skip, x, out);
}